// Round 8
// baseline (197.710 us; speedup 1.0000x reference)
//
#include <hip/hip_runtime.h>

typedef unsigned short u16;
typedef unsigned int u32;
typedef short bf16x8 __attribute__((ext_vector_type(8)));
typedef float f32x4 __attribute__((ext_vector_type(4)));
typedef u32 u32x4 __attribute__((ext_vector_type(4)));

#define MFMA16(a, b, c) __builtin_amdgcn_mfma_f32_16x16x32_bf16((a), (b), (c), 0, 0, 0)

__device__ __forceinline__ u16 f2bf(float f) {
  u32 u = __builtin_bit_cast(u32, f);
  u += 0x7FFFu + ((u >> 16) & 1u);
  return (u16)(u >> 16);
}
// packed f32x2 -> bf16x2, round-half-up (R6-proven; ties differ from RNE by
// <=1 ulp, absmax headroom 3x). NOTE (R4 post-mortem): inline-asm
// v_cvt_pk_bf16_f32 produced NaN on this toolchain -- do NOT reintroduce it.
__device__ __forceinline__ u32 pk2bf(float a, float b) {
  u32 ua = __builtin_bit_cast(u32, a) + 0x8000u;
  u32 ub = __builtin_bit_cast(u32, b) + 0x8000u;
  return (ua >> 16) | (ub & 0xFFFF0000u);
}

// ws byte offsets
#define WS_MGF   0         // bf16 [8 jt][64 lane][8 j]  frags of M-stack  (8192 B)
#define WS_WT1F  8192      // bf16 [8 ot][2 cs][4 kt][64][8]  B-frags W1, k=c   (65536 B)
#define WS_WT2F  73728     // bf16 [8 ot][4 s][4 kt][64][8]   B-frags W2, k=o1  (131072 B)
#define WS_B1    204800    // f32 [128]  bias1 + T0-fold
#define WS_B2    205312    // f32 [128]  bias2 + T0-fold

// R7 contraction-order flip: out = sum_kt M[kt] @ (X @ W[kt]).
// The inner product Z[kt] = X @ W[kt] is partitioned by output-o (the per-wave
// split), so Z is WAVE-PRIVATE -> the cross-wave Y exchange and its ~12
// barriers disappear. W1 frags are now k=c (c-major); W2 frags k=o1.
__global__ void prep_kernel(const float* __restrict__ adj,
                            const float* __restrict__ adj_bias,
                            const float* __restrict__ w1,
                            const float* __restrict__ b1,
                            const float* __restrict__ w2,
                            const float* __restrict__ b2,
                            char* __restrict__ ws) {
  const int tid = threadIdx.x;
  if (blockIdx.x == 0) {
    __shared__ float sa[1024], Ls[1024], L2s[1024], L3s[1024], sdre[32];
    float bias = adj_bias[0];
    for (int i = tid; i < 1024; i += 256) sa[i] = fmaxf(adj[i] + bias, 0.0f);
    __syncthreads();
    if (tid < 32) {
      float s = 0.0f;
      for (int c = 0; c < 32; ++c) s += sa[tid * 32 + c];
      sdre[tid] = 1.0f / sqrtf(s + 1e-5f);
    }
    __syncthreads();
    for (int i = tid; i < 1024; i += 256) {
      int n = i >> 5, c = i & 31;
      Ls[i] = (n == c ? 1.0f : 0.0f) - sdre[n] * sa[i] * sdre[c];
    }
    __syncthreads();
    for (int i = tid; i < 1024; i += 256) {
      int r = i >> 5, c = i & 31;
      float s = 0.0f;
      for (int m = 0; m < 32; ++m) s += Ls[r * 32 + m] * Ls[m * 32 + c];
      L2s[i] = s;
    }
    __syncthreads();
    for (int i = tid; i < 1024; i += 256) {
      int r = i >> 5, c = i & 31;
      float s = 0.0f;
      for (int m = 0; m < 32; ++m) s += L2s[r * 32 + m] * Ls[m * 32 + c];
      L3s[i] = s;
    }
    __syncthreads();
    // M stacked [128x32]: rows 0-31 I, 32-63 L, 64-95 2L^2-I, 96-127 4L^3-3L.
    // MGf[jt][lane][j] = M[row=jt*16+(lane&15)][n=(lane>>4)*8+j]
    // (B-frag: col=(kt,np), k=n -- serves the transposed node-mix directly)
    u16* MGf = (u16*)(ws + WS_MGF);
    for (int i = tid; i < 4096; i += 256) {
      int jt = i >> 9, lane = (i >> 3) & 63, j = i & 7;
      int col = jt * 16 + (lane & 15);
      int k = ((lane >> 4) << 3) + j;
      int kk = col >> 5, np = col & 31;
      float v;
      if (kk == 0)      v = (np == k) ? 1.0f : 0.0f;
      else if (kk == 1) v = Ls[np * 32 + k];
      else if (kk == 2) v = 2.0f * L2s[np * 32 + k] - (np == k ? 1.0f : 0.0f);
      else              v = 4.0f * L3s[np * 32 + k] - 3.0f * Ls[np * 32 + k];
      MGf[i] = f2bf(v);
    }
    float* B1 = (float*)(ws + WS_B1);
    float* B2 = (float*)(ws + WS_B2);
    if (tid < 128) {
      float s = b1[tid];
      for (int c = 0; c < 60; ++c) s += w1[(c * 5) * 128 + tid];
      B1[tid] = s;
    } else {
      int o = tid - 128;
      float s = b2[o];
      for (int c = 0; c < 128; ++c) s += w2[(c * 5) * 128 + o];
      B2[o] = s;
    }
  } else {
    u16* WT1F = (u16*)(ws + WS_WT1F);
    u16* WT2F = (u16*)(ws + WS_WT2F);
    int g = (blockIdx.x - 1) * 256 + tid;
    // WT1F bits: j[0:3) lane[3:9) kt[9:11) cs[11:12) ot8[12:15)
    // B-frag of W1[kt] (k=c): element = w1[(c*5+kt+1)*128 + o],
    //   c = cs*32 + q*8 + j (0 if c>=60), o = ot8*16 + (lane&15)
    for (int i = g; i < 32768; i += 16 * 256) {
      int j = i & 7, lane = (i >> 3) & 63, kt = (i >> 9) & 3;
      int cs = (i >> 11) & 1, ot8 = i >> 12;
      int q = lane >> 4;
      int c = cs * 32 + q * 8 + j;
      int o = ot8 * 16 + (lane & 15);
      WT1F[i] = (c < 60) ? f2bf(w1[(c * 5 + kt + 1) * 128 + o]) : (u16)0;
    }
    // WT2F bits: j[0:3) lane[3:9) kt[9:11) s[11:13) ot8[13:16)
    // B-frag of W2[kt] (k=o1): element = w2[(o1*5+kt+1)*128 + o2],
    //   o1 = s*32 + q*8 + j, o2 = ot8*16 + (lane&15)
    for (int i = g; i < 65536; i += 16 * 256) {
      int j = i & 7, lane = (i >> 3) & 63, kt = (i >> 9) & 3;
      int s = (i >> 11) & 3, ot8 = i >> 13;
      int q = lane >> 4;
      int o1 = s * 32 + q * 8 + j;
      int o2 = ot8 * 16 + (lane & 15);
      WT2F[i] = f2bf(w2[(o1 * 5 + kt + 1) * 128 + o2]);
    }
  }
}

// 2 batches/block, 4 waves, wave w owns o-tiles 2w,2w+1 in BOTH layers.
// Per (bat,kt): Z = X @ W[kt] (8 MFMA) -> wave-private Zt LDS (Ht-style
// swizzled write, b128 read, no barrier) -> transposed node-mix
// acc^T[o][np] += MFMA(Zt-frag, MGf) (4 MFMA). Only 2 barriers/block.
// LDS (33856 B, 4 blocks/CU):
//   Hn [2 bat][32 np][136] u16  (17408 B; 136-stride => conflict-free b128 reads)
//   Zt [4 w][2 bat][32 o][32 n] u16, slot16 swizzle ps = s ^ (l15&3) ^ (l15>>2)
//   red: dedicated 64 B tail (no overlay: waves are unsynchronized here)
__global__ __launch_bounds__(256, 4) void dgcnn_kernel(
    const float* __restrict__ x,
    const char* __restrict__ ws,
    const float* __restrict__ fc_w,
    const float* __restrict__ fc_b,
    float* __restrict__ out) {
  __shared__ __align__(16) char arena[33856];
  u16* Hn = (u16*)arena;              // [2][32][136] = 17408 B
  u16* Zt = (u16*)(arena + 17408);    // [4][2][1024 u16] = 16384 B
  float* red = (float*)(arena + 33792);

  const u16* MGf  = (const u16*)(ws + WS_MGF);
  const u16* WT1F = (const u16*)(ws + WS_WT1F);
  const u16* WT2F = (const u16*)(ws + WS_WT2F);
  const float* bias1 = (const float*)(ws + WS_B1);
  const float* bias2 = (const float*)(ws + WS_B2);

  const int tid = threadIdx.x;
  const int w = tid >> 6, lane = tid & 63;
  const int l15 = lane & 15, q = lane >> 4;
  const int b0 = blockIdx.x * 2;
  const f32x4 z4 = {0.0f, 0.0f, 0.0f, 0.0f};

  u16* zt0 = Zt + (w * 2 + 0) * 1024;
  u16* zt1 = Zt + (w * 2 + 1) * 1024;

  // Zt addressing (Ht-proven full-rank slot swizzle).
  // write: C tile [mtl][ot]: row o=ot*16+l15, n=mtl*16+q*4+r (uint2 along n)
  // read:  A-frag row-tile otl: row o=otl*16+l15, n=q*8+j (one b128)
  const int zswz = (l15 & 3) ^ (l15 >> 2);
  int zws[2][2], zrd[2];
#pragma unroll
  for (int mtl = 0; mtl < 2; ++mtl)
#pragma unroll
    for (int ot = 0; ot < 2; ++ot)
      zws[mtl][ot] = (ot * 16 + l15) * 32 + (((mtl * 2 + (q >> 1)) ^ zswz) * 8) + (q & 1) * 4;
  zrd[0] = l15 * 32 + ((q ^ zswz) * 8);
  zrd[1] = (16 + l15) * 32 + ((q ^ zswz) * 8);

#define ZPACK(dst, t)                                        \
  { uint2 v_;                                                \
    v_.x = pk2bf((t)[0], (t)[1]);                            \
    v_.y = pk2bf((t)[2], (t)[3]);                            \
    *(uint2*)&(dst) = v_; }

  // ---------------- layer 1 ----------------
  f32x4 acc1[2][2][2];  // [bat][otl][npt], out1^T: row o1, col np
#pragma unroll
  for (int a = 0; a < 2; ++a)
#pragma unroll
    for (int b = 0; b < 2; ++b)
#pragma unroll
      for (int c = 0; c < 2; ++c) acc1[a][b][c] = z4;

#pragma unroll
  for (int bat = 0; bat < 2; ++bat) {
    u16* z = bat ? zt1 : zt0;
    // X A-frags straight from global: lane(q,l15) row n=l15+16mtl, c=cs*32+q*8..+7
    bf16x8 xf[2][2];
#pragma unroll
    for (int mtl = 0; mtl < 2; ++mtl)
#pragma unroll
      for (int cs = 0; cs < 2; ++cs) {
        int n = mtl * 16 + l15, c0 = cs * 32 + q * 8;
        const float* p = x + (size_t)(b0 + bat) * 1920 + n * 60 + c0;
        float4 u = *(const float4*)p;
        float4 v = (c0 < 56) ? *(const float4*)(p + 4)
                             : make_float4(0.0f, 0.0f, 0.0f, 0.0f);
        u32x4 pk = {pk2bf(u.x, u.y), pk2bf(u.z, u.w), pk2bf(v.x, v.y), pk2bf(v.z, v.w)};
        xf[mtl][cs] = __builtin_bit_cast(bf16x8, pk);
      }
#pragma unroll
    for (int kt = 0; kt < 4; ++kt) {
      bf16x8 m0 = *(const bf16x8*)(MGf + (kt * 2 + 0) * 512 + lane * 8);
      bf16x8 m1 = *(const bf16x8*)(MGf + (kt * 2 + 1) * 512 + lane * 8);
      const u16* wp = WT1F + (size_t)((2 * w) * 8 + kt) * 512 + lane * 8;
      bf16x8 wf00 = *(const bf16x8*)wp;             // ot=0 cs=0
      bf16x8 wf01 = *(const bf16x8*)(wp + 2048);    // ot=0 cs=1
      bf16x8 wf10 = *(const bf16x8*)(wp + 4096);    // ot=1 cs=0
      bf16x8 wf11 = *(const bf16x8*)(wp + 6144);    // ot=1 cs=1
      // Z = X @ W1[kt]: C[n][o], tiles [mtl][ot], k=64 over c
      f32x4 zc00 = MFMA16(xf[0][0], wf00, z4); zc00 = MFMA16(xf[0][1], wf01, zc00);
      f32x4 zc01 = MFMA16(xf[0][0], wf10, z4); zc01 = MFMA16(xf[0][1], wf11, zc01);
      f32x4 zc10 = MFMA16(xf[1][0], wf00, z4); zc10 = MFMA16(xf[1][1], wf01, zc10);
      f32x4 zc11 = MFMA16(xf[1][0], wf10, z4); zc11 = MFMA16(xf[1][1], wf11, zc11);
      ZPACK(z[zws[0][0]], zc00);
      ZPACK(z[zws[0][1]], zc01);
      ZPACK(z[zws[1][0]], zc10);
      ZPACK(z[zws[1][1]], zc11);
      // node-mix (transposed): acc1^T[o1][np] += Zt[o1][n] x M[kt][np][n]
      bf16x8 za0 = *(const bf16x8*)&z[zrd[0]];
      bf16x8 za1 = *(const bf16x8*)&z[zrd[1]];
      acc1[bat][0][0] = MFMA16(za0, m0, acc1[bat][0][0]);
      acc1[bat][0][1] = MFMA16(za0, m1, acc1[bat][0][1]);
      acc1[bat][1][0] = MFMA16(za1, m0, acc1[bat][1][0]);
      acc1[bat][1][1] = MFMA16(za1, m1, acc1[bat][1][1]);
    }
  }

  // ---- bias1+relu -> Hn[bat][np][o1] (lane holds 4 consecutive o1) ----
#pragma unroll
  for (int bat = 0; bat < 2; ++bat)
#pragma unroll
    for (int otl = 0; otl < 2; ++otl) {
      int ob = (2 * w + otl) * 16 + q * 4;
      float4 bv = *(const float4*)&bias1[ob];
#pragma unroll
      for (int npt = 0; npt < 2; ++npt) {
        f32x4 a = acc1[bat][otl][npt];
        uint2 v;
        v.x = pk2bf(fmaxf(a[0] + bv.x, 0.0f), fmaxf(a[1] + bv.y, 0.0f));
        v.y = pk2bf(fmaxf(a[2] + bv.z, 0.0f), fmaxf(a[3] + bv.w, 0.0f));
        *(uint2*)&Hn[bat * 4352 + (npt * 16 + l15) * 136 + ob] = v;
      }
    }
  __syncthreads();  // barrier #1: Hn visible to all waves

  // ---------------- layer 2 ----------------
  f32x4 acc2[2][2][2];  // [bat][ot2][npt], out2^T
#pragma unroll
  for (int a = 0; a < 2; ++a)
#pragma unroll
    for (int b = 0; b < 2; ++b)
#pragma unroll
      for (int c = 0; c < 2; ++c) acc2[a][b][c] = z4;

#pragma unroll
  for (int bat = 0; bat < 2; ++bat) {
    u16* z = bat ? zt1 : zt0;
    // Hn A-frags: row np=l15+16ntl, k o1 = s*32+q*8..+7
    bf16x8 hf[2][4];
#pragma unroll
    for (int ntl = 0; ntl < 2; ++ntl)
#pragma unroll
      for (int s = 0; s < 4; ++s)
        hf[ntl][s] = *(const bf16x8*)&Hn[bat * 4352 + (ntl * 16 + l15) * 136 + s * 32 + q * 8];
#pragma unroll
    for (int kt = 0; kt < 4; ++kt) {
      bf16x8 m0 = *(const bf16x8*)(MGf + (kt * 2 + 0) * 512 + lane * 8);
      bf16x8 m1 = *(const bf16x8*)(MGf + (kt * 2 + 1) * 512 + lane * 8);
      // Z2 = H @ W2[kt]: C[np][o2], tiles [ntl][ot2], k=128 over o1
      f32x4 zc00 = z4, zc01 = z4, zc10 = z4, zc11 = z4;
#pragma unroll
      for (int s = 0; s < 4; ++s) {
        const u16* wp = WT2F + (size_t)((2 * w) * 16 + s * 4 + kt) * 512 + lane * 8;
        bf16x8 w0  = *(const bf16x8*)wp;            // ot2=0
        bf16x8 w1f = *(const bf16x8*)(wp + 8192);   // ot2=1
        zc00 = MFMA16(hf[0][s], w0, zc00);
        zc01 = MFMA16(hf[0][s], w1f, zc01);
        zc10 = MFMA16(hf[1][s], w0, zc10);
        zc11 = MFMA16(hf[1][s], w1f, zc11);
      }
      ZPACK(z[zws[0][0]], zc00);
      ZPACK(z[zws[0][1]], zc01);
      ZPACK(z[zws[1][0]], zc10);
      ZPACK(z[zws[1][1]], zc11);
      bf16x8 za0 = *(const bf16x8*)&z[zrd[0]];
      bf16x8 za1 = *(const bf16x8*)&z[zrd[1]];
      acc2[bat][0][0] = MFMA16(za0, m0, acc2[bat][0][0]);
      acc2[bat][0][1] = MFMA16(za0, m1, acc2[bat][0][1]);
      acc2[bat][1][0] = MFMA16(za1, m0, acc2[bat][1][0]);
      acc2[bat][1][1] = MFMA16(za1, m1, acc2[bat][1][1]);
    }
  }

  // ---- epilogue: bias2+relu in regs, fc directly from accumulators ----
  float p0A = 0.0f, p1A = 0.0f, p0B = 0.0f, p1B = 0.0f;
#pragma unroll
  for (int ot = 0; ot < 2; ++ot) {
    int ob = (2 * w + ot) * 16 + q * 4;  // o2 base, 4 contiguous per lane
    float4 bv = *(const float4*)&bias2[ob];
#pragma unroll
    for (int nt = 0; nt < 2; ++nt) {
      int n = nt * 16 + l15;
      float4 w0 = *(const float4*)&fc_w[n * 128 + ob];
      float4 w1v = *(const float4*)&fc_w[4096 + n * 128 + ob];
      float hA0 = fmaxf(acc2[0][ot][nt][0] + bv.x, 0.0f);
      float hA1 = fmaxf(acc2[0][ot][nt][1] + bv.y, 0.0f);
      float hA2 = fmaxf(acc2[0][ot][nt][2] + bv.z, 0.0f);
      float hA3 = fmaxf(acc2[0][ot][nt][3] + bv.w, 0.0f);
      float hB0 = fmaxf(acc2[1][ot][nt][0] + bv.x, 0.0f);
      float hB1 = fmaxf(acc2[1][ot][nt][1] + bv.y, 0.0f);
      float hB2 = fmaxf(acc2[1][ot][nt][2] + bv.z, 0.0f);
      float hB3 = fmaxf(acc2[1][ot][nt][3] + bv.w, 0.0f);
      p0A = fmaf(hA0, w0.x, fmaf(hA1, w0.y, fmaf(hA2, w0.z, fmaf(hA3, w0.w, p0A))));
      p1A = fmaf(hA0, w1v.x, fmaf(hA1, w1v.y, fmaf(hA2, w1v.z, fmaf(hA3, w1v.w, p1A))));
      p0B = fmaf(hB0, w0.x, fmaf(hB1, w0.y, fmaf(hB2, w0.z, fmaf(hB3, w0.w, p0B))));
      p1B = fmaf(hB0, w1v.x, fmaf(hB1, w1v.y, fmaf(hB2, w1v.z, fmaf(hB3, w1v.w, p1B))));
    }
  }
#pragma unroll
  for (int off = 32; off >= 1; off >>= 1) {
    p0A += __shfl_xor(p0A, off);
    p1A += __shfl_xor(p1A, off);
    p0B += __shfl_xor(p0B, off);
    p1B += __shfl_xor(p1B, off);
  }
  if (lane == 0) {
    red[w * 4 + 0] = p0A;
    red[w * 4 + 1] = p1A;
    red[w * 4 + 2] = p0B;
    red[w * 4 + 3] = p1B;
  }
  __syncthreads();  // barrier #2
  if (tid < 4) {
    float s = red[tid] + red[4 + tid] + red[8 + tid] + red[12 + tid] + fc_b[tid & 1];
    out[(b0 + (tid >> 1)) * 2 + (tid & 1)] = s;
  }
}

extern "C" void kernel_launch(void* const* d_in, const int* in_sizes, int n_in,
                              void* d_out, int out_size, void* d_ws, size_t ws_size,
                              hipStream_t stream) {
  const float* x        = (const float*)d_in[0];
  const float* adj      = (const float*)d_in[1];
  const float* adj_bias = (const float*)d_in[2];
  const float* w1       = (const float*)d_in[3];
  const float* b1       = (const float*)d_in[4];
  const float* w2       = (const float*)d_in[5];
  const float* b2       = (const float*)d_in[6];
  const float* fc_w     = (const float*)d_in[7];
  const float* fc_b     = (const float*)d_in[8];
  float* out = (float*)d_out;
  char* ws   = (char*)d_ws;

  prep_kernel<<<17, 256, 0, stream>>>(adj, adj_bias, w1, b1, w2, b2, ws);
  dgcnn_kernel<<<4096, 256, 0, stream>>>(x, ws, fc_w, fc_b, out);
}